// Round 4
// baseline (844.840 us; speedup 1.0000x reference)
//
#include <hip/hip_runtime.h>
#include <math.h>

#define DIMC 128
#define FINC 78
#define REPW 1152        // 9 * 128
#define SCAN_TILE 1024   // elements per scan tile (256 threads x 4)

typedef __attribute__((ext_vector_type(8))) short short8x;
typedef __attribute__((ext_vector_type(4))) float f32x4;
typedef unsigned int u32;
typedef const __attribute__((address_space(1))) u32* gas_u32p;
typedef __attribute__((address_space(3))) u32* las_u32p;

__device__ inline float b2f(unsigned short u) {
    union { unsigned int i; float f; } v; v.i = ((unsigned int)u) << 16; return v.f;
}
__device__ inline unsigned short f2b(float f) {
    union { float f; unsigned int i; } v; v.f = f;
    unsigned int r = (v.i + 0x7FFFu + ((v.i >> 16) & 1u)) >> 16;
    return (unsigned short)r;
}
__device__ inline float upk2(unsigned short h, unsigned short l) { return b2f(h) + b2f(l); }

// 16B global -> LDS DMA. HW semantics: LDS dest = wave-uniform base + lane*16;
// our per-lane dest is linear in lane order (tid*16), matching the constraint.
__device__ __forceinline__ void gld16(const void* g, void* l) {
    __builtin_amdgcn_global_load_lds((gas_u32p)g, (las_u32p)l, 16, 0, 0);
}

// ---------------- setup kernels ----------------

__global__ void k_fill_int(int* __restrict__ p, int v, int n) {
    int i = blockIdx.x * blockDim.x + threadIdx.x;
    if (i < n) p[i] = v;
}

__global__ void k_fill(float* __restrict__ p, float v, int n) {
    int i = blockIdx.x * blockDim.x + threadIdx.x;
    if (i < n) p[i] = v;
}

__global__ void k_count(const int* __restrict__ dst, int* __restrict__ cnt, int E) {
    int e = blockIdx.x * blockDim.x + threadIdx.x;
    if (e < E) atomicAdd(&cnt[dst[e]], 1);
}

__launch_bounds__(256)
__global__ void k_tilesum(const int* __restrict__ cnt, int* __restrict__ tileSum, int N) {
    __shared__ int red[256];
    int base = blockIdx.x * SCAN_TILE;
    int s = 0;
    for (int i = threadIdx.x; i < SCAN_TILE; i += 256) {
        int idx = base + i;
        if (idx < N) s += cnt[idx];
    }
    red[threadIdx.x] = s;
    __syncthreads();
    for (int d = 128; d > 0; d >>= 1) {
        if (threadIdx.x < d) red[threadIdx.x] += red[threadIdx.x + d];
        __syncthreads();
    }
    if (threadIdx.x == 0) tileSum[blockIdx.x] = red[0];
}

__launch_bounds__(256)
__global__ void k_tilescan(const int* __restrict__ tileSum, int* __restrict__ tileOff,
                           int* __restrict__ rowptr, int T, int N) {
    __shared__ int sh[256];
    int t = threadIdx.x;
    int orig = (t < T) ? tileSum[t] : 0;
    sh[t] = orig;
    __syncthreads();
    for (int d = 1; d < 256; d <<= 1) {
        int v = (t >= d) ? sh[t - d] : 0;
        __syncthreads();
        sh[t] += v;
        __syncthreads();
    }
    if (t < T) tileOff[t] = sh[t] - orig;
    if (t == 255) rowptr[N] = sh[255];
}

__launch_bounds__(256)
__global__ void k_tileemit(const int* __restrict__ cnt, const int* __restrict__ tileOff,
                           int* __restrict__ rowptr, int* __restrict__ cursor,
                           float* __restrict__ dis, int N) {
    __shared__ int sh[256];
    int t = threadIdx.x;
    int base = blockIdx.x * SCAN_TILE;
    int idx0 = base + t * 4;
    int v0 = 0, v1 = 0, v2 = 0, v3 = 0;
    if (idx0 + 3 < N) {
        int4 v = *(const int4*)(cnt + idx0);
        v0 = v.x; v1 = v.y; v2 = v.z; v3 = v.w;
    } else {
        if (idx0 + 0 < N) v0 = cnt[idx0 + 0];
        if (idx0 + 1 < N) v1 = cnt[idx0 + 1];
        if (idx0 + 2 < N) v2 = cnt[idx0 + 2];
        if (idx0 + 3 < N) v3 = cnt[idx0 + 3];
    }
    int s0 = v0, s1 = s0 + v1, s2 = s1 + v2, s3 = s2 + v3;
    sh[t] = s3;
    __syncthreads();
    for (int d = 1; d < 256; d <<= 1) {
        int v = (t >= d) ? sh[t - d] : 0;
        __syncthreads();
        sh[t] += v;
        __syncthreads();
    }
    int gbase = tileOff[blockIdx.x] + ((t == 0) ? 0 : sh[t - 1]);
    int ex[4] = {0, s0, s1, s2};
    int vv[4] = {v0, v1, v2, v3};
#pragma unroll
    for (int j = 0; j < 4; ++j) {
        int idx = idx0 + j;
        if (idx < N) {
            int r = gbase + ex[j];
            rowptr[idx] = r;
            cursor[idx] = r;
            dis[idx] = rsqrtf((float)vv[j] + 1.0f);
        }
    }
}

__global__ void k_scatter(const int* __restrict__ src, const int* __restrict__ dst,
                          int* __restrict__ cursor, int* __restrict__ col, int E) {
    int e = blockIdx.x * blockDim.x + threadIdx.x;
    if (e < E) {
        int pos = atomicAdd(&cursor[dst[e]], 1);
        col[pos] = src[e];
    }
}

__global__ void k_bounds(const int* __restrict__ batch, int* __restrict__ start, int N, int G) {
    int g = blockIdx.x * blockDim.x + threadIdx.x;
    if (g <= G) {
        int lo = 0, hi = N;
        while (lo < hi) { int mid = (lo + hi) >> 1; if (batch[mid] < g) lo = mid + 1; else hi = mid; }
        start[g] = lo;
    }
}

// ---------------- weight split: fp32 W[k][n] -> transposed bf16 hi/lo [n][k] ----------------

__global__ void k_cvt_w(const float* __restrict__ s0, const float* __restrict__ s1,
                        const float* __restrict__ s2, const float* __restrict__ s3,
                        const float* __restrict__ s4, const float* __restrict__ s5,
                        const float* __restrict__ s6, const float* __restrict__ s7,
                        unsigned short* __restrict__ whi, unsigned short* __restrict__ wlo) {
    int my = blockIdx.y;
    const float* src; int Ksrc, KP; size_t dstoff;
    const size_t o96 = (size_t)128 * 96, o128 = (size_t)128 * 128;
    switch (my) {
        case 0: src = s0; Ksrc = 78;  KP = 96;  dstoff = 0; break;
        case 1: src = s1; Ksrc = 78;  KP = 96;  dstoff = o96; break;
        case 2: src = s2; Ksrc = 128; KP = 128; dstoff = 2 * o96; break;
        case 3: src = s3; Ksrc = 128; KP = 128; dstoff = 2 * o96 + o128; break;
        case 4: src = s4; Ksrc = 128; KP = 128; dstoff = 2 * o96 + 2 * o128; break;
        case 5: src = s5; Ksrc = 128; KP = 128; dstoff = 2 * o96 + 3 * o128; break;
        case 6: src = s6; Ksrc = 128; KP = 128; dstoff = 2 * o96 + 4 * o128; break;
        default: src = s7; Ksrc = 128; KP = 128; dstoff = 2 * o96 + 5 * o128; break;
    }
    int i = blockIdx.x * blockDim.x + threadIdx.x;
    if (i < 128 * KP) {
        int n = i / KP, k = i - n * KP;
        float v = (k < Ksrc) ? src[(size_t)k * DIMC + n] : 0.f;
        unsigned short hi = f2b(v);
        unsigned short lo = f2b(v - b2f(hi));
        whi[dstoff + i] = hi;
        wlo[dstoff + i] = lo;
    }
}

// ---------------- pack x: fp32 [N][78] -> hi/lo planes [NP][96] (zero-padded cols) ----------------

__global__ void k_pack_x(const float* __restrict__ x, unsigned short* __restrict__ xhi,
                         unsigned short* __restrict__ xlo, int N) {
    int i = blockIdx.x * blockDim.x + threadIdx.x;
    int r = i / 24, cc = (i - r * 24) * 4;
    if (r >= N) return;
    float v[4];
#pragma unroll
    for (int j = 0; j < 4; ++j) { int k = cc + j; v[j] = (k < FINC) ? x[(size_t)r * FINC + k] : 0.f; }
    unsigned short h[4], l[4];
#pragma unroll
    for (int j = 0; j < 4; ++j) { h[j] = f2b(v[j]); l[j] = f2b(v[j] - b2f(h[j])); }
    *(ushort4*)(xhi + (size_t)r * 96 + cc) = make_ushort4(h[0], h[1], h[2], h[3]);
    *(ushort4*)(xlo + (size_t)r * 96 + cc) = make_ushort4(l[0], l[1], l[2], l[3]);
}

// ---------------- MFMA GEMM on pre-split bf16 planes ----------------
// A: Ahi/Alo [>=ceil128(N)][KP] (pad rows may be garbage: outputs guarded).
// B: Bhi/Blo [128][KP]. C = epi(A @ B^T): bias (per col), relu, rowScale, col stats.
// Output packed hi/lo planes [.][128].
//
// Staging: global_load_lds 16B, double-buffered, counted vmcnt + raw barriers.
// LDS layout per plane: 512 units of 16B, unit u = g*128 + r holds global octet
// (g ^ (r&3)) of row r (XOR applied on the per-lane GLOBAL source address; LDS
// stays linear in thread order so the DMA constraint holds).
// MFMA operands are SWAPPED (mfma(W,A)): lane(lm,q) reg i owns
// C[row = wr+yt*16+lm][col = wc+xt*16+q*4+i] -> 4 consecutive cols -> ushort4 stores.

template<int KP>
__launch_bounds__(256, 2)
__global__ void k_gemm_pk(const unsigned short* __restrict__ Ahi, const unsigned short* __restrict__ Alo,
                          const unsigned short* __restrict__ Bhi, const unsigned short* __restrict__ Blo,
                          const float* __restrict__ bias, const float* __restrict__ rowScale,
                          float* __restrict__ statsOut,
                          unsigned short* __restrict__ Ohi, unsigned short* __restrict__ Olo,
                          int N, int doRelu) {
    constexpr int NT = KP / 32;
    __shared__ unsigned short lds[2][4][4096];   // 64 KB: [dbuf][Ahi,Alo,Bhi,Blo][512 units x 8 shorts]
    const int tid = threadIdx.x;
    const int wave = tid >> 6, lane = tid & 63;
    const int lm = lane & 15, q = lane >> 4;
    const int wr = (wave >> 1) * 64, wc = (wave & 1) * 64;
    const int row0 = blockIdx.x * 128;

    const int rr = tid & 127;
    const int g0 = tid >> 7;                      // unit0 slot-g in {0,1}; unit1 is g0+2
    const int o0 = ((g0 ^ (rr & 3)) << 3);        // source octet offsets (shorts)
    const int o1 = (((2 + g0) ^ (rr & 3)) << 3);
    const size_t arow = (size_t)(row0 + rr) * KP;
    const size_t brow = (size_t)rr * KP;
    const int u0 = tid << 3;                      // LDS unit offsets (shorts)
    const int u1 = (256 + tid) << 3;

    f32x4 acc[4][4];
#pragma unroll
    for (int a = 0; a < 4; ++a)
#pragma unroll
        for (int b = 0; b < 4; ++b) acc[a][b] = (f32x4){0.f, 0.f, 0.f, 0.f};

    auto stage = [&](int c, int d) {
        const int cb = c << 5;
        gld16(Ahi + arow + cb + o0, &lds[d][0][u0]);
        gld16(Ahi + arow + cb + o1, &lds[d][0][u1]);
        gld16(Alo + arow + cb + o0, &lds[d][1][u0]);
        gld16(Alo + arow + cb + o1, &lds[d][1][u1]);
        gld16(Bhi + brow + cb + o0, &lds[d][2][u0]);
        gld16(Bhi + brow + cb + o1, &lds[d][2][u1]);
        gld16(Blo + brow + cb + o0, &lds[d][3][u0]);
        gld16(Blo + brow + cb + o1, &lds[d][3][u1]);
    };

    stage(0, 0);
#pragma unroll
    for (int t = 0; t < NT; ++t) {
        const int cur = t & 1;
        if (t + 1 < NT) {
            stage(t + 1, cur ^ 1);
            asm volatile("s_waitcnt vmcnt(8)" ::: "memory");   // chunk t landed; next 8 in flight
        } else {
            asm volatile("s_waitcnt vmcnt(0)" ::: "memory");
        }
        __builtin_amdgcn_s_barrier();
        __builtin_amdgcn_sched_barrier(0);

        short8x ah[4], al[4], bh[4], bl[4];
#pragma unroll
        for (int yt = 0; yt < 4; ++yt) {
            int m = wr + yt * 16 + lm;
            int sl = ((q ^ (m & 3)) * 128 + m) << 3;
            ah[yt] = *(const short8x*)&lds[cur][0][sl];
            al[yt] = *(const short8x*)&lds[cur][1][sl];
        }
#pragma unroll
        for (int xt = 0; xt < 4; ++xt) {
            int n = wc + xt * 16 + lm;
            int sl = ((q ^ (n & 3)) * 128 + n) << 3;
            bh[xt] = *(const short8x*)&lds[cur][2][sl];
            bl[xt] = *(const short8x*)&lds[cur][3][sl];
        }
#pragma unroll
        for (int xt = 0; xt < 4; ++xt)
#pragma unroll
            for (int yt = 0; yt < 4; ++yt) {
                acc[xt][yt] = __builtin_amdgcn_mfma_f32_16x16x32_bf16(bh[xt], ah[yt], acc[xt][yt], 0, 0, 0);
                acc[xt][yt] = __builtin_amdgcn_mfma_f32_16x16x32_bf16(bh[xt], al[yt], acc[xt][yt], 0, 0, 0);
                acc[xt][yt] = __builtin_amdgcn_mfma_f32_16x16x32_bf16(bl[xt], ah[yt], acc[xt][yt], 0, 0, 0);
            }
        __builtin_amdgcn_s_barrier();   // protect buf being overwritten by next stage
    }

    // epilogue: bias -> relu -> rowScale -> stats + packed ushort4 stores
    float cs[4][4], cq[4][4];
#pragma unroll
    for (int xt = 0; xt < 4; ++xt)
#pragma unroll
        for (int i = 0; i < 4; ++i) { cs[xt][i] = 0.f; cq[xt][i] = 0.f; }

#pragma unroll
    for (int yt = 0; yt < 4; ++yt) {
        int m = wr + yt * 16 + lm;
        int gr = row0 + m;
        if (gr < N) {
            float sc = rowScale ? rowScale[gr] : 1.f;
#pragma unroll
            for (int xt = 0; xt < 4; ++xt) {
                int nb = wc + xt * 16 + q * 4;
                unsigned short h4[4], l4[4];
#pragma unroll
                for (int i = 0; i < 4; ++i) {
                    float v = acc[xt][yt][i];
                    if (bias) v += bias[nb + i];
                    if (doRelu) v = fmaxf(v, 0.f);
                    v *= sc;
                    cs[xt][i] += v; cq[xt][i] = fmaf(v, v, cq[xt][i]);
                    h4[i] = f2b(v);
                    l4[i] = f2b(v - b2f(h4[i]));
                }
                *(ushort4*)(Ohi + (size_t)gr * DIMC + nb) = make_ushort4(h4[0], h4[1], h4[2], h4[3]);
                *(ushort4*)(Olo + (size_t)gr * DIMC + nb) = make_ushort4(l4[0], l4[1], l4[2], l4[3]);
            }
        }
    }

    if (statsOut) {
        float* sSt = (float*)&lds[0][0][0];
        __syncthreads();
        sSt[tid] = 0.f;
        __syncthreads();
#pragma unroll
        for (int xt = 0; xt < 4; ++xt)
#pragma unroll
            for (int i = 0; i < 4; ++i) {
                float vs = cs[xt][i], vq = cq[xt][i];
#pragma unroll
                for (int o = 1; o < 16; o <<= 1) { vs += __shfl_xor(vs, o); vq += __shfl_xor(vq, o); }
                if (lm == 0) {
                    int nb = wc + xt * 16 + q * 4 + i;
                    atomicAdd(&sSt[nb], vs);
                    atomicAdd(&sSt[DIMC + nb], vq);
                }
            }
        __syncthreads();
        atomicAdd(&statsOut[tid], sSt[tid]);
    }
}

// ---------------- BN coefficients: sums -> (scale, shift) ----------------

__global__ void k_bn_coef(const float* __restrict__ bnsum, const float* __restrict__ gamma,
                          const float* __restrict__ beta, float* __restrict__ coef, float invN) {
    int c = threadIdx.x;  // 128
    float mu  = bnsum[c] * invN;
    float var = bnsum[128 + c] * invN - mu * mu;
    float inv = rsqrtf(var + 1e-5f);
    float s = gamma[c] * inv;
    coef[c] = s;
    coef[128 + c] = beta[c] - mu * s;
}

// ---- fold BN affine into next layer's W1: W'[n][k] = s[k]*w1[k][n], cvec[n] = sum_k t[k]*w1[k][n]

__global__ void k_fold_w(const float* __restrict__ w1, const float* __restrict__ coefL,
                         unsigned short* __restrict__ fwhi, unsigned short* __restrict__ fwlo,
                         float* __restrict__ cvec) {
    __shared__ float red[128];
    int n = blockIdx.x, k = threadIdx.x;
    float w = w1[(size_t)k * DIMC + n];
    float ws = w * coefL[k];
    unsigned short h = f2b(ws);
    fwhi[(size_t)n * DIMC + k] = h;
    fwlo[(size_t)n * DIMC + k] = f2b(ws - b2f(h));
    red[k] = w * coefL[DIMC + k];
    __syncthreads();
    for (int d = 64; d > 0; d >>= 1) { if (k < d) red[k] += red[k + d]; __syncthreads(); }
    if (k == 0) cvec[n] = red[0];
}

// ---------------- CSR gather aggregation on packed hi/lo planes ----------------

__global__ void k_gather_gcn_pk(const unsigned short* __restrict__ Thi, const unsigned short* __restrict__ Tlo,
                                const int* __restrict__ rowptr, const int* __restrict__ col,
                                const float* __restrict__ dis, const float* __restrict__ bias,
                                unsigned short* __restrict__ Ohi, unsigned short* __restrict__ Olo, int N) {
    int i = blockIdx.x * blockDim.x + threadIdx.x;
    int node = i >> 5, cc = (i & 31) << 2;
    if (node >= N) return;
    int s = rowptr[node], e = rowptr[node + 1];
    size_t sp = (size_t)node * DIMC + cc;
    ushort4 h = *(const ushort4*)(Thi + sp), l = *(const ushort4*)(Tlo + sp);
    float a0 = upk2(h.x, l.x), a1 = upk2(h.y, l.y), a2 = upk2(h.z, l.z), a3 = upk2(h.w, l.w);
    for (int k = s; k < e; ++k) {
        size_t p = (size_t)col[k] * DIMC + cc;
        ushort4 hh = *(const ushort4*)(Thi + p), ll = *(const ushort4*)(Tlo + p);
        a0 += upk2(hh.x, ll.x); a1 += upk2(hh.y, ll.y); a2 += upk2(hh.z, ll.z); a3 += upk2(hh.w, ll.w);
    }
    float d = dis[node];
    float4 b = ((const float4*)bias)[i & 31];
    float v0 = fmaxf(fmaf(a0, d, b.x), 0.f);
    float v1 = fmaxf(fmaf(a1, d, b.y), 0.f);
    float v2 = fmaxf(fmaf(a2, d, b.z), 0.f);
    float v3 = fmaxf(fmaf(a3, d, b.w), 0.f);
    unsigned short oh[4] = {f2b(v0), f2b(v1), f2b(v2), f2b(v3)};
    *(ushort4*)(Ohi + sp) = make_ushort4(oh[0], oh[1], oh[2], oh[3]);
    *(ushort4*)(Olo + sp) = make_ushort4(f2b(v0 - b2f(oh[0])), f2b(v1 - b2f(oh[1])),
                                         f2b(v2 - b2f(oh[2])), f2b(v3 - b2f(oh[3])));
}

__global__ void k_gather_gin_pk(const unsigned short* __restrict__ Thi, const unsigned short* __restrict__ Tlo,
                                const int* __restrict__ rowptr, const int* __restrict__ col,
                                const float* __restrict__ bias,
                                unsigned short* __restrict__ Ohi, unsigned short* __restrict__ Olo, int N) {
    int i = blockIdx.x * blockDim.x + threadIdx.x;
    int node = i >> 5, cc = (i & 31) << 2;
    if (node >= N) return;
    int s = rowptr[node], e = rowptr[node + 1];
    size_t sp = (size_t)node * DIMC + cc;
    ushort4 h = *(const ushort4*)(Thi + sp), l = *(const ushort4*)(Tlo + sp);
    float a0 = upk2(h.x, l.x), a1 = upk2(h.y, l.y), a2 = upk2(h.z, l.z), a3 = upk2(h.w, l.w);
    for (int k = s; k < e; ++k) {
        size_t p = (size_t)col[k] * DIMC + cc;
        ushort4 hh = *(const ushort4*)(Thi + p), ll = *(const ushort4*)(Tlo + p);
        a0 += upk2(hh.x, ll.x); a1 += upk2(hh.y, ll.y); a2 += upk2(hh.z, ll.z); a3 += upk2(hh.w, ll.w);
    }
    float4 b = ((const float4*)bias)[i & 31];
    float v0 = fmaxf(a0 + b.x, 0.f);
    float v1 = fmaxf(a1 + b.y, 0.f);
    float v2 = fmaxf(a2 + b.z, 0.f);
    float v3 = fmaxf(a3 + b.w, 0.f);
    unsigned short oh[4] = {f2b(v0), f2b(v1), f2b(v2), f2b(v3)};
    *(ushort4*)(Ohi + sp) = make_ushort4(oh[0], oh[1], oh[2], oh[3]);
    *(ushort4*)(Olo + sp) = make_ushort4(f2b(v0 - b2f(oh[0])), f2b(v1 - b2f(oh[1])),
                                         f2b(v2 - b2f(oh[2])), f2b(v3 - b2f(oh[3])));
}

// ---------------- segment max ----------------

__global__ void k_segmax_gin_all_pk(const unsigned short* __restrict__ h0h, const unsigned short* __restrict__ h0l,
                                    const unsigned short* __restrict__ h1h, const unsigned short* __restrict__ h1l,
                                    const unsigned short* __restrict__ h2h, const unsigned short* __restrict__ h2l,
                                    const float* __restrict__ coef, const int* __restrict__ start,
                                    float* __restrict__ out) {
    int g = blockIdx.x, c = threadIdx.x;
    float s0 = coef[c],       t0 = coef[128 + c];
    float s1 = coef[256 + c], t1 = coef[384 + c];
    float s2 = coef[512 + c], t2 = coef[640 + c];
    int s = start[g], e = start[g + 1];
    float m0 = -INFINITY, m1 = -INFINITY, m2 = -INFINITY, mm = -INFINITY, me = -INFINITY;
    for (int n = s; n < e; ++n) {
        size_t idx = (size_t)n * DIMC + c;
        float a0 = fmaf(upk2(h0h[idx], h0l[idx]), s0, t0);
        float a1 = fmaf(upk2(h1h[idx], h1l[idx]), s1, t1);
        float a2 = fmaf(upk2(h2h[idx], h2l[idx]), s2, t2);
        m0 = fmaxf(m0, a0); m1 = fmaxf(m1, a1); m2 = fmaxf(m2, a2);
        mm = fmaxf(mm, a0 * a1 * a2);
        me = fmaxf(me, a0 + a1 + a2);
    }
    size_t o = (size_t)g * REPW + c;
    out[o]            = m0;
    out[o + 1 * DIMC] = m1;
    out[o + 2 * DIMC] = m2;
    out[o + 3 * DIMC] = mm;
    out[o + 4 * DIMC] = me;
}

__global__ void k_segmax_gcn_pk(const unsigned short* __restrict__ g1h, const unsigned short* __restrict__ g1l,
                                const unsigned short* __restrict__ g2h, const unsigned short* __restrict__ g2l,
                                const int* __restrict__ start, float* __restrict__ out) {
    int g = blockIdx.x, c = threadIdx.x;
    int s = start[g], e = start[g + 1];
    float m1 = -INFINITY, m2 = -INFINITY, ma = -INFINITY, mm = -INFINITY;
    for (int n = s; n < e; ++n) {
        size_t idx = (size_t)n * DIMC + c;
        float a = upk2(g1h[idx], g1l[idx]);
        float b = upk2(g2h[idx], g2l[idx]);
        m1 = fmaxf(m1, a); m2 = fmaxf(m2, b);
        ma = fmaxf(ma, a + b); mm = fmaxf(mm, a * b);
    }
    size_t o = (size_t)g * REPW + c;
    out[o + 5 * DIMC] = m1;
    out[o + 6 * DIMC] = m2;
    out[o + 7 * DIMC] = ma;
    out[o + 8 * DIMC] = mm;
}

// ---------------- launch ----------------

extern "C" void kernel_launch(void* const* d_in, const int* in_sizes, int n_in,
                              void* d_out, int out_size, void* d_ws, size_t ws_size,
                              hipStream_t stream) {
    const float* x       = (const float*)d_in[0];
    const int*   ei      = (const int*)d_in[1];
    const int*   batch   = (const int*)d_in[2];
    const float* gcn1_W  = (const float*)d_in[4];
    const float* gcn1_b  = (const float*)d_in[5];
    const float* gcn2_W  = (const float*)d_in[6];
    const float* gcn2_b  = (const float*)d_in[7];
    const float* gin0_w1 = (const float*)d_in[8];
    const float* gin0_b1 = (const float*)d_in[9];
    const float* gin0_w2 = (const float*)d_in[10];
    const float* gin0_b2 = (const float*)d_in[11];
    const float* gin_w1  = (const float*)d_in[12];
    const float* gin_b1  = (const float*)d_in[13];
    const float* gin_w2  = (const float*)d_in[14];
    const float* gin_b2  = (const float*)d_in[15];
    const float* bn_g    = (const float*)d_in[16];
    const float* bn_b    = (const float*)d_in[17];
    float* out = (float*)d_out;

    const int N = in_sizes[0] / FINC;   // 100000
    const int E = in_sizes[1] / 2;      // 400000
    const int G = out_size / REPW;      // 2500
    const int NP = (N + 127) & ~127;    // padded rows for DMA staging (pad garbage; outputs guarded)
    const int* srcv = ei;
    const int* dstv = ei + E;

    // Workspace kept at the previously-passing footprint (~260 MB):
    // packed-x planes ALIAS the H1 planes (disjoint lifetimes); T and H2
    // are sized N rows (never GEMM A-inputs, DMA never reads their pads).
    char* ws = (char*)d_ws;
    size_t off = 0;
    auto alloc = [&](size_t bytes) { char* p = ws + off; off += (bytes + 255) & ~(size_t)255; return p; };
    int*   cnt     = (int*)alloc((size_t)N * 4);
    int*   rowptr  = (int*)alloc(((size_t)N + 1) * 4);
    int*   cursor  = (int*)alloc((size_t)N * 4);
    int*   col     = (int*)alloc((size_t)E * 4);
    float* dis     = (float*)alloc((size_t)N * 4);
    float* bnsum   = (float*)alloc(768 * 4);
    float* coef    = (float*)alloc(768 * 4);
    float* cvec    = (float*)alloc(128 * 4);
    int*   start   = (int*)alloc(((size_t)G + 1) * 4);
    int*   tileSum = (int*)alloc(256 * 4);
    int*   tileOff = (int*)alloc(256 * 4);
    const size_t o96 = (size_t)128 * 96, o128 = (size_t)128 * 128;
    const size_t wtElems = 2 * o96 + 6 * o128;
    unsigned short* whi  = (unsigned short*)alloc(wtElems * 2);
    unsigned short* wlo  = (unsigned short*)alloc(wtElems * 2);
    unsigned short* fwhi = (unsigned short*)alloc(o128 * 2);
    unsigned short* fwlo = (unsigned short*)alloc(o128 * 2);
    const size_t pbytesP = (size_t)NP * DIMC * 2;   // NP rows (GEMM A-inputs)
    const size_t pbytesN = (size_t)N  * DIMC * 2;   // N rows  (never GEMM A-inputs)
    unsigned short* Thi = (unsigned short*)alloc(pbytesN);
    unsigned short* Tlo = (unsigned short*)alloc(pbytesN);
    unsigned short* Zhi = (unsigned short*)alloc(pbytesP);   // GCN g1 / GIN z (GEMM input)
    unsigned short* Zlo = (unsigned short*)alloc(pbytesP);
    unsigned short* H0h = (unsigned short*)alloc(pbytesP);   // GCN g2 then GIN h0 (GEMM input)
    unsigned short* H0l = (unsigned short*)alloc(pbytesP);
    unsigned short* H1h = (unsigned short*)alloc(pbytesP);   // GIN h1 (GEMM input); hosts packed x early
    unsigned short* H1l = (unsigned short*)alloc(pbytesP);
    unsigned short* H2h = (unsigned short*)alloc(pbytesN);
    unsigned short* H2l = (unsigned short*)alloc(pbytesN);
    // packed x aliases H1 (x dead before H1 is first written; NP*96 <= NP*128)
    unsigned short* xhi = H1h;
    unsigned short* xlo = H1l;
    (void)ws_size; (void)n_in;

    const size_t woff[8] = {0, o96, 2 * o96, 2 * o96 + o128, 2 * o96 + 2 * o128,
                            2 * o96 + 3 * o128, 2 * o96 + 4 * o128, 2 * o96 + 5 * o128};
    // order: gcn1, gin0_w1, gcn2, gin0_w2, gin_w1[0], gin_w1[1], gin_w2[0], gin_w2[1]

    const int T = 256;
    auto cdiv = [](long a, long b) { return (int)((a + b - 1) / b); };
    const int gemmGrid = cdiv(N, 128);
    const int gatherGrid = cdiv((long)N * 32, T);
    const int nTiles = cdiv(N, SCAN_TILE);
    const float invN = 1.0f / (float)N;

    // ---- CSR build + norms + graph bounds + weight split + x pack ----
    k_fill_int<<<cdiv(N, T), T, 0, stream>>>(cnt, 0, N);
    k_count<<<cdiv(E, T), T, 0, stream>>>(dstv, cnt, E);
    k_tilesum<<<nTiles, T, 0, stream>>>(cnt, tileSum, N);
    k_tilescan<<<1, T, 0, stream>>>(tileSum, tileOff, rowptr, nTiles, N);
    k_tileemit<<<nTiles, T, 0, stream>>>(cnt, tileOff, rowptr, cursor, dis, N);
    k_scatter<<<cdiv(E, T), T, 0, stream>>>(srcv, dstv, cursor, col, E);
    k_bounds<<<cdiv(G + 1, T), T, 0, stream>>>(batch, start, N, G);
    k_fill<<<3, T, 0, stream>>>(bnsum, 0.f, 768);
    {
        dim3 g(64, 8);
        k_cvt_w<<<g, T, 0, stream>>>(gcn1_W, gin0_w1, gcn2_W, gin0_w2,
                                     gin_w1, gin_w1 + o128, gin_w2, gin_w2 + o128, whi, wlo);
    }
    k_pack_x<<<cdiv((long)N * 24, T), T, 0, stream>>>(x, xhi, xlo, N);

    // ---- GCN branch ----
    k_gemm_pk<96><<<gemmGrid, T, 0, stream>>>(xhi, xlo, whi + woff[0], wlo + woff[0],
                                              nullptr, dis, nullptr, Thi, Tlo, N, 0);
    k_gather_gcn_pk<<<gatherGrid, T, 0, stream>>>(Thi, Tlo, rowptr, col, dis, gcn1_b, Zhi, Zlo, N);  // g1
    k_gemm_pk<128><<<gemmGrid, T, 0, stream>>>(Zhi, Zlo, whi + woff[2], wlo + woff[2],
                                               nullptr, dis, nullptr, Thi, Tlo, N, 0);
    k_gather_gcn_pk<<<gatherGrid, T, 0, stream>>>(Thi, Tlo, rowptr, col, dis, gcn2_b, H0h, H0l, N);  // g2
    k_segmax_gcn_pk<<<G, DIMC, 0, stream>>>(Zhi, Zlo, H0h, H0l, start, out);                         // groups 5..8

    // ---- GIN layer 0 ----
    k_gemm_pk<96><<<gemmGrid, T, 0, stream>>>(xhi, xlo, whi + woff[1], wlo + woff[1],
                                              nullptr, nullptr, nullptr, Thi, Tlo, N, 0);
    k_gather_gin_pk<<<gatherGrid, T, 0, stream>>>(Thi, Tlo, rowptr, col, gin0_b1, Zhi, Zlo, N);
    k_gemm_pk<128><<<gemmGrid, T, 0, stream>>>(Zhi, Zlo, whi + woff[3], wlo + woff[3],
                                               gin0_b2, nullptr, bnsum, H0h, H0l, N, 1);
    k_bn_coef<<<1, DIMC, 0, stream>>>(bnsum, bn_g, bn_b, coef, invN);
    k_fold_w<<<DIMC, DIMC, 0, stream>>>(gin_w1, coef, fwhi, fwlo, cvec);

    // ---- GIN layer 1 (BN folded into weights: scaled W, cvec as GEMM bias) ----
    // x (aliased in H1) is dead from here on; H1 written below.
    k_gemm_pk<128><<<gemmGrid, T, 0, stream>>>(H0h, H0l, fwhi, fwlo,
                                               cvec, nullptr, nullptr, Thi, Tlo, N, 0);
    k_gather_gin_pk<<<gatherGrid, T, 0, stream>>>(Thi, Tlo, rowptr, col, gin_b1, Zhi, Zlo, N);
    k_gemm_pk<128><<<gemmGrid, T, 0, stream>>>(Zhi, Zlo, whi + woff[6], wlo + woff[6],
                                               gin_b2, nullptr, bnsum + 256, H1h, H1l, N, 1);
    k_bn_coef<<<1, DIMC, 0, stream>>>(bnsum + 256, bn_g + DIMC, bn_b + DIMC, coef + 256, invN);
    k_fold_w<<<DIMC, DIMC, 0, stream>>>(gin_w1 + o128, coef + 256, fwhi, fwlo, cvec);

    // ---- GIN layer 2 ----
    k_gemm_pk<128><<<gemmGrid, T, 0, stream>>>(H1h, H1l, fwhi, fwlo,
                                               cvec, nullptr, nullptr, Thi, Tlo, N, 0);
    k_gather_gin_pk<<<gatherGrid, T, 0, stream>>>(Thi, Tlo, rowptr, col, gin_b1 + DIMC, Zhi, Zlo, N);
    k_gemm_pk<128><<<gemmGrid, T, 0, stream>>>(Zhi, Zlo, whi + woff[7], wlo + woff[7],
                                               gin_b2 + DIMC, nullptr, bnsum + 512, H2h, H2l, N, 1);
    k_bn_coef<<<1, DIMC, 0, stream>>>(bnsum + 512, bn_g + 2 * DIMC, bn_b + 2 * DIMC, coef + 512, invN);

    k_segmax_gin_all_pk<<<G, DIMC, 0, stream>>>(H0h, H0l, H1h, H1l, H2h, H2l, coef, start, out);     // groups 0..4
}

// Round 5
// 817.977 us; speedup vs baseline: 1.0328x; 1.0328x over previous
//
#include <hip/hip_runtime.h>
#include <math.h>

#define DIMC 128
#define FINC 78
#define REPW 1152        // 9 * 128
#define SCAN_TILE 1024   // elements per scan tile (256 threads x 4)

typedef __attribute__((ext_vector_type(8))) short short8x;
typedef __attribute__((ext_vector_type(4))) float f32x4;
typedef unsigned int u32;
typedef const __attribute__((address_space(1))) u32* gas_u32p;
typedef __attribute__((address_space(3))) u32* las_u32p;

__device__ inline float b2f(unsigned short u) {
    union { unsigned int i; float f; } v; v.i = ((unsigned int)u) << 16; return v.f;
}
__device__ inline unsigned short f2b(float f) {
    union { float f; unsigned int i; } v; v.f = f;
    unsigned int r = (v.i + 0x7FFFu + ((v.i >> 16) & 1u)) >> 16;
    return (unsigned short)r;
}

// 16B global -> LDS DMA (dest = wave-uniform base + lane*16; our dest is linear in tid).
__device__ __forceinline__ void gld16(const void* g, void* l) {
    __builtin_amdgcn_global_load_lds((gas_u32p)g, (las_u32p)l, 16, 0, 0);
}

// ---------------- setup kernels ----------------

__global__ void k_fill_int(int* __restrict__ p, int v, int n) {
    int i = blockIdx.x * blockDim.x + threadIdx.x;
    if (i < n) p[i] = v;
}

__global__ void k_fill(float* __restrict__ p, float v, int n) {
    int i = blockIdx.x * blockDim.x + threadIdx.x;
    if (i < n) p[i] = v;
}

__global__ void k_count(const int* __restrict__ dst, int* __restrict__ cnt, int E) {
    int e = blockIdx.x * blockDim.x + threadIdx.x;
    if (e < E) atomicAdd(&cnt[dst[e]], 1);
}

__launch_bounds__(256)
__global__ void k_tilesum(const int* __restrict__ cnt, int* __restrict__ tileSum, int N) {
    __shared__ int red[256];
    int base = blockIdx.x * SCAN_TILE;
    int s = 0;
    for (int i = threadIdx.x; i < SCAN_TILE; i += 256) {
        int idx = base + i;
        if (idx < N) s += cnt[idx];
    }
    red[threadIdx.x] = s;
    __syncthreads();
    for (int d = 128; d > 0; d >>= 1) {
        if (threadIdx.x < d) red[threadIdx.x] += red[threadIdx.x + d];
        __syncthreads();
    }
    if (threadIdx.x == 0) tileSum[blockIdx.x] = red[0];
}

__launch_bounds__(256)
__global__ void k_tilescan(const int* __restrict__ tileSum, int* __restrict__ tileOff,
                           int* __restrict__ rowptr, int T, int N) {
    __shared__ int sh[256];
    int t = threadIdx.x;
    int orig = (t < T) ? tileSum[t] : 0;
    sh[t] = orig;
    __syncthreads();
    for (int d = 1; d < 256; d <<= 1) {
        int v = (t >= d) ? sh[t - d] : 0;
        __syncthreads();
        sh[t] += v;
        __syncthreads();
    }
    if (t < T) tileOff[t] = sh[t] - orig;
    if (t == 255) rowptr[N] = sh[255];
}

__launch_bounds__(256)
__global__ void k_tileemit(const int* __restrict__ cnt, const int* __restrict__ tileOff,
                           int* __restrict__ rowptr, int* __restrict__ cursor,
                           float* __restrict__ dis, int N) {
    __shared__ int sh[256];
    int t = threadIdx.x;
    int base = blockIdx.x * SCAN_TILE;
    int idx0 = base + t * 4;
    int v0 = 0, v1 = 0, v2 = 0, v3 = 0;
    if (idx0 + 3 < N) {
        int4 v = *(const int4*)(cnt + idx0);
        v0 = v.x; v1 = v.y; v2 = v.z; v3 = v.w;
    } else {
        if (idx0 + 0 < N) v0 = cnt[idx0 + 0];
        if (idx0 + 1 < N) v1 = cnt[idx0 + 1];
        if (idx0 + 2 < N) v2 = cnt[idx0 + 2];
        if (idx0 + 3 < N) v3 = cnt[idx0 + 3];
    }
    int s0 = v0, s1 = s0 + v1, s2 = s1 + v2, s3 = s2 + v3;
    sh[t] = s3;
    __syncthreads();
    for (int d = 1; d < 256; d <<= 1) {
        int v = (t >= d) ? sh[t - d] : 0;
        __syncthreads();
        sh[t] += v;
        __syncthreads();
    }
    int gbase = tileOff[blockIdx.x] + ((t == 0) ? 0 : sh[t - 1]);
    int ex[4] = {0, s0, s1, s2};
    int vv[4] = {v0, v1, v2, v3};
#pragma unroll
    for (int j = 0; j < 4; ++j) {
        int idx = idx0 + j;
        if (idx < N) {
            int r = gbase + ex[j];
            rowptr[idx] = r;
            cursor[idx] = r;
            dis[idx] = rsqrtf((float)vv[j] + 1.0f);
        }
    }
}

__global__ void k_scatter(const int* __restrict__ src, const int* __restrict__ dst,
                          int* __restrict__ cursor, int* __restrict__ col, int E) {
    int e = blockIdx.x * blockDim.x + threadIdx.x;
    if (e < E) {
        int pos = atomicAdd(&cursor[dst[e]], 1);
        col[pos] = src[e];
    }
}

__global__ void k_bounds(const int* __restrict__ batch, int* __restrict__ start, int N, int G) {
    int g = blockIdx.x * blockDim.x + threadIdx.x;
    if (g <= G) {
        int lo = 0, hi = N;
        while (lo < hi) { int mid = (lo + hi) >> 1; if (batch[mid] < g) lo = mid + 1; else hi = mid; }
        start[g] = lo;
    }
}

// ---------------- weight split: fp32 W[k][n] -> transposed bf16 hi/lo [n][k] ----------------

__global__ void k_cvt_w(const float* __restrict__ s0, const float* __restrict__ s1,
                        const float* __restrict__ s2, const float* __restrict__ s3,
                        const float* __restrict__ s4, const float* __restrict__ s5,
                        const float* __restrict__ s6, const float* __restrict__ s7,
                        unsigned short* __restrict__ whi, unsigned short* __restrict__ wlo) {
    int my = blockIdx.y;
    const float* src; int Ksrc, KP; size_t dstoff;
    const size_t o96 = (size_t)128 * 96, o128 = (size_t)128 * 128;
    switch (my) {
        case 0: src = s0; Ksrc = 78;  KP = 96;  dstoff = 0; break;
        case 1: src = s1; Ksrc = 78;  KP = 96;  dstoff = o96; break;
        case 2: src = s2; Ksrc = 128; KP = 128; dstoff = 2 * o96; break;
        case 3: src = s3; Ksrc = 128; KP = 128; dstoff = 2 * o96 + o128; break;
        case 4: src = s4; Ksrc = 128; KP = 128; dstoff = 2 * o96 + 2 * o128; break;
        case 5: src = s5; Ksrc = 128; KP = 128; dstoff = 2 * o96 + 3 * o128; break;
        case 6: src = s6; Ksrc = 128; KP = 128; dstoff = 2 * o96 + 4 * o128; break;
        default: src = s7; Ksrc = 128; KP = 128; dstoff = 2 * o96 + 5 * o128; break;
    }
    int i = blockIdx.x * blockDim.x + threadIdx.x;
    if (i < 128 * KP) {
        int n = i / KP, k = i - n * KP;
        float v = (k < Ksrc) ? src[(size_t)k * DIMC + n] : 0.f;
        unsigned short hi = f2b(v);
        unsigned short lo = f2b(v - b2f(hi));
        whi[dstoff + i] = hi;
        wlo[dstoff + i] = lo;
    }
}

// ---------------- pack x: fp32 [N][78] -> hi/lo planes [N][96] (zero-padded cols) ----------------

__global__ void k_pack_x(const float* __restrict__ x, unsigned short* __restrict__ xhi,
                         unsigned short* __restrict__ xlo, int N) {
    int i = blockIdx.x * blockDim.x + threadIdx.x;
    int r = i / 24, cc = (i - r * 24) * 4;
    if (r >= N) return;
    float v[4];
#pragma unroll
    for (int j = 0; j < 4; ++j) { int k = cc + j; v[j] = (k < FINC) ? x[(size_t)r * FINC + k] : 0.f; }
    unsigned short h[4], l[4];
#pragma unroll
    for (int j = 0; j < 4; ++j) { h[j] = f2b(v[j]); l[j] = f2b(v[j] - b2f(h[j])); }
    *(ushort4*)(xhi + (size_t)r * 96 + cc) = make_ushort4(h[0], h[1], h[2], h[3]);
    *(ushort4*)(xlo + (size_t)r * 96 + cc) = make_ushort4(l[0], l[1], l[2], l[3]);
}

// ---------------- MFMA GEMM: fp32 (or pre-split) A, split-bf16 B, fp32 C ----------------
// Block = 256 threads = 4 waves, 64 rows; wave w owns rows [blk*64 + w*16, +16) x all 128 cols.
// A: loaded global->reg directly in MFMA b-frag layout (lane(q,lm): row lm, k-octet q),
//    fp32 path converts to bf16 hi/lo in-register; SPLITA path reads pre-split planes.
// B: whi/wlo [128 n][KP k], staged per 32-K chunk to LDS via 16B DMA with source-XOR
//    swizzle (round-4 scheme, 0 bank conflicts), double-buffered, counted vmcnt.
// C = epi(A @ B^T): bias, relu, rowScale, optional column stats. fp32 stores.
// MFMA convention (HW-verified round 4): acc = mfma(b_frag=W, a_frag=A) ->
// C[row = lm][col = ct*16 + q*4 + i].

template<int KP, bool SPLITA, bool STATS>
__launch_bounds__(256, 3)
__global__ void k_gemm_f(const void* __restrict__ A0, const void* __restrict__ A1,
                         const unsigned short* __restrict__ Bhi, const unsigned short* __restrict__ Blo,
                         const float* __restrict__ bias, const float* __restrict__ rowScale,
                         float* __restrict__ statsOut, float* __restrict__ C,
                         int N, int doRelu) {
    constexpr int NT = KP / 32;
    __shared__ unsigned short lds[2][2][4096];   // 32 KB: [dbuf][Bhi,Blo][512 units x 8 shorts]
    __shared__ float sStats[256];
    const int tid = threadIdx.x;
    const int wave = tid >> 6, lane = tid & 63;
    const int lm = lane & 15, q = lane >> 4;
    const int row = blockIdx.x * 64 + wave * 16 + lm;
    const int am = (row < N) ? row : (N - 1);

    // B staging addressing (identical to round-4 proven scheme)
    const int rr = tid & 127;
    const int g0 = tid >> 7;
    const int o0 = ((g0 ^ (rr & 3)) << 3);
    const int o1 = (((2 + g0) ^ (rr & 3)) << 3);
    const size_t brow = (size_t)rr * KP;
    const int u0 = tid << 3;
    const int u1 = (256 + tid) << 3;

    auto stageB = [&](int c, int d) {
        const int cb = c << 5;
        gld16(Bhi + brow + cb + o0, &lds[d][0][u0]);
        gld16(Bhi + brow + cb + o1, &lds[d][0][u1]);
        gld16(Blo + brow + cb + o0, &lds[d][1][u0]);
        gld16(Blo + brow + cb + o1, &lds[d][1][u1]);
    };

    const unsigned short* aph = nullptr;
    const unsigned short* apl = nullptr;
    const float* apf = nullptr;
    if constexpr (SPLITA) {
        aph = (const unsigned short*)A0 + (size_t)am * KP;
        apl = (const unsigned short*)A1 + (size_t)am * KP;
    } else {
        apf = (const float*)A0 + (size_t)am * KP;
    }

    short8x pah, pal, nah, nal;
    float4 pf0, pf1, nf0, nf1;

    auto loadA = [&](int c, short8x& h, short8x& l, float4& f0, float4& f1) {
        int ko = c * 32 + q * 8;
        if constexpr (SPLITA) {
            h = *(const short8x*)(aph + ko);
            l = *(const short8x*)(apl + ko);
        } else {
            f0 = *(const float4*)(apf + ko);
            f1 = *(const float4*)(apf + ko + 4);
        }
    };

    f32x4 acc[8];
#pragma unroll
    for (int i = 0; i < 8; ++i) acc[i] = (f32x4){0.f, 0.f, 0.f, 0.f};

    stageB(0, 0);
    loadA(0, pah, pal, pf0, pf1);
    __builtin_amdgcn_sched_barrier(0);

#pragma unroll
    for (int t = 0; t < NT; ++t) {
        const int cur = t & 1;
        if (t + 1 < NT) {
            stageB(t + 1, cur ^ 1);
            loadA(t + 1, nah, nal, nf0, nf1);
            __builtin_amdgcn_sched_barrier(0);
            asm volatile("s_waitcnt vmcnt(6)" ::: "memory");   // chunk t's 6 loads landed
        } else {
            asm volatile("s_waitcnt vmcnt(0)" ::: "memory");
        }
        __builtin_amdgcn_s_barrier();
        __builtin_amdgcn_sched_barrier(0);

        short8x ah, al;
        if constexpr (SPLITA) {
            ah = pah; al = pal;
        } else {
            float f[8] = {pf0.x, pf0.y, pf0.z, pf0.w, pf1.x, pf1.y, pf1.z, pf1.w};
#pragma unroll
            for (int j = 0; j < 8; ++j) {
                unsigned short h = f2b(f[j]);
                ah[j] = (short)h;
                al[j] = (short)f2b(f[j] - b2f(h));
            }
        }
#pragma unroll
        for (int ct = 0; ct < 8; ++ct) {
            int n = ct * 16 + lm;
            int sl = ((q ^ (n & 3)) * 128 + n) << 3;
            short8x bh = *(const short8x*)&lds[cur][0][sl];
            short8x bl = *(const short8x*)&lds[cur][1][sl];
            acc[ct] = __builtin_amdgcn_mfma_f32_16x16x32_bf16(bh, ah, acc[ct], 0, 0, 0);
            acc[ct] = __builtin_amdgcn_mfma_f32_16x16x32_bf16(bh, al, acc[ct], 0, 0, 0);
            acc[ct] = __builtin_amdgcn_mfma_f32_16x16x32_bf16(bl, ah, acc[ct], 0, 0, 0);
        }
        __builtin_amdgcn_s_barrier();   // protect LDS buf about to be overwritten
        pah = nah; pal = nal; pf0 = nf0; pf1 = nf1;
    }

    // epilogue: bias -> relu -> rowScale, fp32 stores, optional column stats
    if constexpr (STATS) { sStats[tid] = 0.f; __syncthreads(); }
    const bool valid = row < N;
    float sc = 1.f;
    if (rowScale) sc = rowScale[valid ? row : 0];

#pragma unroll
    for (int ct = 0; ct < 8; ++ct) {
        float vv[4];
#pragma unroll
        for (int i = 0; i < 4; ++i) {
            float v = acc[ct][i];
            if (bias) v += bias[ct * 16 + q * 4 + i];
            if (doRelu) v = fmaxf(v, 0.f);
            v *= sc;
            vv[i] = valid ? v : 0.f;
        }
        if (valid)
            *(float4*)(C + (size_t)row * DIMC + ct * 16 + q * 4) =
                make_float4(vv[0], vv[1], vv[2], vv[3]);
        if constexpr (STATS) {
#pragma unroll
            for (int i = 0; i < 4; ++i) {
                float vs = vv[i], vq = vv[i] * vv[i];
#pragma unroll
                for (int o = 1; o < 16; o <<= 1) { vs += __shfl_xor(vs, o); vq += __shfl_xor(vq, o); }
                if (lm == 0) {
                    int colg = ct * 16 + q * 4 + i;
                    atomicAdd(&sStats[colg], vs);
                    atomicAdd(&sStats[DIMC + colg], vq);
                }
            }
        }
    }
    if constexpr (STATS) {
        __syncthreads();
        atomicAdd(&statsOut[tid], sStats[tid]);
    }
}

// ---------------- BN coefficients: sums -> (scale, shift) ----------------

__global__ void k_bn_coef(const float* __restrict__ bnsum, const float* __restrict__ gamma,
                          const float* __restrict__ beta, float* __restrict__ coef, float invN) {
    int c = threadIdx.x;  // 128
    float mu  = bnsum[c] * invN;
    float var = bnsum[128 + c] * invN - mu * mu;
    float inv = rsqrtf(var + 1e-5f);
    float s = gamma[c] * inv;
    coef[c] = s;
    coef[128 + c] = beta[c] - mu * s;
}

// ---- fold BN affine into next layer's W1: W'[n][k] = s[k]*w1[k][n], cvec[n] = sum_k t[k]*w1[k][n]

__global__ void k_fold_w(const float* __restrict__ w1, const float* __restrict__ coefL,
                         unsigned short* __restrict__ fwhi, unsigned short* __restrict__ fwlo,
                         float* __restrict__ cvec) {
    __shared__ float red[128];
    int n = blockIdx.x, k = threadIdx.x;
    float w = w1[(size_t)k * DIMC + n];
    float ws = w * coefL[k];
    unsigned short h = f2b(ws);
    fwhi[(size_t)n * DIMC + k] = h;
    fwlo[(size_t)n * DIMC + k] = f2b(ws - b2f(h));
    red[k] = w * coefL[DIMC + k];
    __syncthreads();
    for (int d = 64; d > 0; d >>= 1) { if (k < d) red[k] += red[k + d]; __syncthreads(); }
    if (k == 0) cvec[n] = red[0];
}

// ---------------- CSR gather aggregation (fp32, round-0 proven) ----------------

__global__ void k_gather_gcn(const float4* __restrict__ t, const int* __restrict__ rowptr,
                             const int* __restrict__ col, const float* __restrict__ dis,
                             const float4* __restrict__ bias, float4* __restrict__ out, int N) {
    int i = blockIdx.x * blockDim.x + threadIdx.x;
    int node = i >> 5, c4 = i & 31;
    if (node >= N) return;
    int s = rowptr[node], e = rowptr[node + 1];
    float4 acc = t[(size_t)node * 32 + c4];
    for (int k = s; k < e; ++k) {
        float4 v = t[(size_t)col[k] * 32 + c4];
        acc.x += v.x; acc.y += v.y; acc.z += v.z; acc.w += v.w;
    }
    float d = dis[node];
    float4 b = bias[c4];
    float4 o;
    o.x = fmaxf(acc.x * d + b.x, 0.f);
    o.y = fmaxf(acc.y * d + b.y, 0.f);
    o.z = fmaxf(acc.z * d + b.z, 0.f);
    o.w = fmaxf(acc.w * d + b.w, 0.f);
    out[(size_t)node * 32 + c4] = o;
}

__global__ void k_gather_gin(const float4* __restrict__ t, const int* __restrict__ rowptr,
                             const int* __restrict__ col, const float4* __restrict__ bias,
                             float4* __restrict__ out, int N) {
    int i = blockIdx.x * blockDim.x + threadIdx.x;
    int node = i >> 5, c4 = i & 31;
    if (node >= N) return;
    int s = rowptr[node], e = rowptr[node + 1];
    float4 acc = t[(size_t)node * 32 + c4];
    for (int k = s; k < e; ++k) {
        float4 v = t[(size_t)col[k] * 32 + c4];
        acc.x += v.x; acc.y += v.y; acc.z += v.z; acc.w += v.w;
    }
    float4 b = bias[c4];
    float4 o;
    o.x = fmaxf(acc.x + b.x, 0.f);
    o.y = fmaxf(acc.y + b.y, 0.f);
    o.z = fmaxf(acc.z + b.z, 0.f);
    o.w = fmaxf(acc.w + b.w, 0.f);
    out[(size_t)node * 32 + c4] = o;
}

// ---------------- segment max (fp32, round-0 proven) ----------------

__global__ void k_segmax_gin_all(const float* __restrict__ h0, const float* __restrict__ h1,
                                 const float* __restrict__ h2, const float* __restrict__ coef,
                                 const int* __restrict__ start, float* __restrict__ out) {
    int g = blockIdx.x, c = threadIdx.x;
    float s0 = coef[c],       t0 = coef[128 + c];
    float s1 = coef[256 + c], t1 = coef[384 + c];
    float s2 = coef[512 + c], t2 = coef[640 + c];
    int s = start[g], e = start[g + 1];
    float m0 = -INFINITY, m1 = -INFINITY, m2 = -INFINITY, mm = -INFINITY, me = -INFINITY;
    for (int n = s; n < e; ++n) {
        size_t idx = (size_t)n * DIMC + c;
        float a0 = fmaf(h0[idx], s0, t0);
        float a1 = fmaf(h1[idx], s1, t1);
        float a2 = fmaf(h2[idx], s2, t2);
        m0 = fmaxf(m0, a0); m1 = fmaxf(m1, a1); m2 = fmaxf(m2, a2);
        mm = fmaxf(mm, a0 * a1 * a2);
        me = fmaxf(me, a0 + a1 + a2);
    }
    size_t o = (size_t)g * REPW + c;
    out[o]            = m0;
    out[o + 1 * DIMC] = m1;
    out[o + 2 * DIMC] = m2;
    out[o + 3 * DIMC] = mm;
    out[o + 4 * DIMC] = me;
}

__global__ void k_segmax_gcn(const float* __restrict__ G1, const float* __restrict__ G2,
                             const int* __restrict__ start, float* __restrict__ out) {
    int g = blockIdx.x, c = threadIdx.x;
    int s = start[g], e = start[g + 1];
    float m1 = -INFINITY, m2 = -INFINITY, ma = -INFINITY, mm = -INFINITY;
    for (int n = s; n < e; ++n) {
        float a = G1[(size_t)n * DIMC + c], b = G2[(size_t)n * DIMC + c];
        m1 = fmaxf(m1, a); m2 = fmaxf(m2, b);
        ma = fmaxf(ma, a + b); mm = fmaxf(mm, a * b);
    }
    size_t o = (size_t)g * REPW + c;
    out[o + 5 * DIMC] = m1;
    out[o + 6 * DIMC] = m2;
    out[o + 7 * DIMC] = ma;
    out[o + 8 * DIMC] = mm;
}

// ---------------- launch ----------------

extern "C" void kernel_launch(void* const* d_in, const int* in_sizes, int n_in,
                              void* d_out, int out_size, void* d_ws, size_t ws_size,
                              hipStream_t stream) {
    const float* x       = (const float*)d_in[0];
    const int*   ei      = (const int*)d_in[1];
    const int*   batch   = (const int*)d_in[2];
    const float* gcn1_W  = (const float*)d_in[4];
    const float* gcn1_b  = (const float*)d_in[5];
    const float* gcn2_W  = (const float*)d_in[6];
    const float* gcn2_b  = (const float*)d_in[7];
    const float* gin0_w1 = (const float*)d_in[8];
    const float* gin0_b1 = (const float*)d_in[9];
    const float* gin0_w2 = (const float*)d_in[10];
    const float* gin0_b2 = (const float*)d_in[11];
    const float* gin_w1  = (const float*)d_in[12];
    const float* gin_b1  = (const float*)d_in[13];
    const float* gin_w2  = (const float*)d_in[14];
    const float* gin_b2  = (const float*)d_in[15];
    const float* bn_g    = (const float*)d_in[16];
    const float* bn_b    = (const float*)d_in[17];
    float* out = (float*)d_out;

    const int N = in_sizes[0] / FINC;   // 100000
    const int E = in_sizes[1] / 2;      // 400000
    const int G = out_size / REPW;      // 2500
    const int* srcv = ei;
    const int* dstv = ei + E;

    // Workspace (~261 MB, within the proven-passing footprint):
    // five fp32 [N][128] planes; packed-x split planes alias h1 (disjoint lifetimes).
    char* ws = (char*)d_ws;
    size_t off = 0;
    auto alloc = [&](size_t bytes) { char* p = ws + off; off += (bytes + 255) & ~(size_t)255; return p; };
    int*   cnt     = (int*)alloc((size_t)N * 4);
    int*   rowptr  = (int*)alloc(((size_t)N + 1) * 4);
    int*   cursor  = (int*)alloc((size_t)N * 4);
    int*   col     = (int*)alloc((size_t)E * 4);
    float* dis     = (float*)alloc((size_t)N * 4);
    float* bnsum   = (float*)alloc(768 * 4);
    float* coef    = (float*)alloc(768 * 4);
    float* cvec    = (float*)alloc(128 * 4);
    int*   start   = (int*)alloc(((size_t)G + 1) * 4);
    int*   tileSum = (int*)alloc(256 * 4);
    int*   tileOff = (int*)alloc(256 * 4);
    const size_t o96 = (size_t)128 * 96, o128 = (size_t)128 * 128;
    const size_t wtElems = 2 * o96 + 6 * o128;
    unsigned short* whi  = (unsigned short*)alloc(wtElems * 2);
    unsigned short* wlo  = (unsigned short*)alloc(wtElems * 2);
    unsigned short* fwhi = (unsigned short*)alloc(o128 * 2);
    unsigned short* fwlo = (unsigned short*)alloc(o128 * 2);
    const size_t fbytes = (size_t)N * DIMC * 4;
    float* bufT = (float*)alloc(fbytes);
    float* bufZ = (float*)alloc(fbytes);
    float* h0   = (float*)alloc(fbytes);
    float* h1   = (float*)alloc(fbytes);   // hosts packed x early (x dead before h1 written)
    float* h2   = (float*)alloc(fbytes);
    unsigned short* xhi = (unsigned short*)h1;                 // N*96*2 = 19.2 MB
    unsigned short* xlo = (unsigned short*)h1 + (size_t)N * 96; // +19.2 MB <= 51.2 MB
    (void)ws_size; (void)n_in;

    const size_t woff[8] = {0, o96, 2 * o96, 2 * o96 + o128, 2 * o96 + 2 * o128,
                            2 * o96 + 3 * o128, 2 * o96 + 4 * o128, 2 * o96 + 5 * o128};
    // order: gcn1, gin0_w1, gcn2, gin0_w2, gin_w1[0], gin_w1[1], gin_w2[0], gin_w2[1]

    const int T = 256;
    auto cdiv = [](long a, long b) { return (int)((a + b - 1) / b); };
    const int gemmGrid = cdiv(N, 64);
    const int gatherGrid = cdiv((long)N * 32, T);
    const int nTiles = cdiv(N, SCAN_TILE);
    const float invN = 1.0f / (float)N;

    // ---- CSR build + norms + graph bounds + weight split + x pack ----
    k_fill_int<<<cdiv(N, T), T, 0, stream>>>(cnt, 0, N);
    k_count<<<cdiv(E, T), T, 0, stream>>>(dstv, cnt, E);
    k_tilesum<<<nTiles, T, 0, stream>>>(cnt, tileSum, N);
    k_tilescan<<<1, T, 0, stream>>>(tileSum, tileOff, rowptr, nTiles, N);
    k_tileemit<<<nTiles, T, 0, stream>>>(cnt, tileOff, rowptr, cursor, dis, N);
    k_scatter<<<cdiv(E, T), T, 0, stream>>>(srcv, dstv, cursor, col, E);
    k_bounds<<<cdiv(G + 1, T), T, 0, stream>>>(batch, start, N, G);
    k_fill<<<3, T, 0, stream>>>(bnsum, 0.f, 768);
    {
        dim3 g(64, 8);
        k_cvt_w<<<g, T, 0, stream>>>(gcn1_W, gin0_w1, gcn2_W, gin0_w2,
                                     gin_w1, gin_w1 + o128, gin_w2, gin_w2 + o128, whi, wlo);
    }
    k_pack_x<<<cdiv((long)N * 24, T), T, 0, stream>>>(x, xhi, xlo, N);

    // ---- GCN branch ----
    k_gemm_f<96, true, false><<<gemmGrid, T, 0, stream>>>(xhi, xlo, whi + woff[0], wlo + woff[0],
                                                          nullptr, dis, nullptr, bufT, N, 0);
    k_gather_gcn<<<gatherGrid, T, 0, stream>>>((const float4*)bufT, rowptr, col, dis,
                                               (const float4*)gcn1_b, (float4*)bufZ, N);   // g1
    k_gemm_f<128, false, false><<<gemmGrid, T, 0, stream>>>(bufZ, nullptr, whi + woff[2], wlo + woff[2],
                                                            nullptr, dis, nullptr, bufT, N, 0);
    k_gather_gcn<<<gatherGrid, T, 0, stream>>>((const float4*)bufT, rowptr, col, dis,
                                               (const float4*)gcn2_b, (float4*)h0, N);     // g2
    k_segmax_gcn<<<G, DIMC, 0, stream>>>(bufZ, h0, start, out);                            // groups 5..8

    // ---- GIN layer 0 ----
    k_gemm_f<96, true, false><<<gemmGrid, T, 0, stream>>>(xhi, xlo, whi + woff[1], wlo + woff[1],
                                                          nullptr, nullptr, nullptr, bufT, N, 0);
    k_gather_gin<<<gatherGrid, T, 0, stream>>>((const float4*)bufT, rowptr, col,
                                               (const float4*)gin0_b1, (float4*)bufZ, N);
    k_gemm_f<128, false, true><<<gemmGrid, T, 0, stream>>>(bufZ, nullptr, whi + woff[3], wlo + woff[3],
                                                           gin0_b2, nullptr, bnsum, h0, N, 1);
    k_bn_coef<<<1, DIMC, 0, stream>>>(bnsum, bn_g, bn_b, coef, invN);
    k_fold_w<<<DIMC, DIMC, 0, stream>>>(gin_w1, coef, fwhi, fwlo, cvec);

    // ---- GIN layer 1 (BN folded into weights; x planes in h1 are dead from here) ----
    k_gemm_f<128, false, false><<<gemmGrid, T, 0, stream>>>(h0, nullptr, fwhi, fwlo,
                                                            cvec, nullptr, nullptr, bufT, N, 0);
    k_gather_gin<<<gatherGrid, T, 0, stream>>>((const float4*)bufT, rowptr, col,
                                               (const float4*)gin_b1, (float4*)bufZ, N);
    k_gemm_f<128, false, true><<<gemmGrid, T, 0, stream>>>(bufZ, nullptr, whi + woff[6], wlo + woff[6],
                                                           gin_b2, nullptr, bnsum + 256, h1, N, 1);
    k_bn_coef<<<1, DIMC, 0, stream>>>(bnsum + 256, bn_g + DIMC, bn_b + DIMC, coef + 256, invN);
    k_fold_w<<<DIMC, DIMC, 0, stream>>>(gin_w1 + o128, coef + 256, fwhi, fwlo, cvec);

    // ---- GIN layer 2 ----
    k_gemm_f<128, false, false><<<gemmGrid, T, 0, stream>>>(h1, nullptr, fwhi, fwlo,
                                                            cvec, nullptr, nullptr, bufT, N, 0);
    k_gather_gin<<<gatherGrid, T, 0, stream>>>((const float4*)bufT, rowptr, col,
                                               (const float4*)(gin_b1 + DIMC), (float4*)bufZ, N);
    k_gemm_f<128, false, true><<<gemmGrid, T, 0, stream>>>(bufZ, nullptr, whi + woff[7], wlo + woff[7],
                                                           gin_b2 + DIMC, nullptr, bnsum + 512, h2, N, 1);
    k_bn_coef<<<1, DIMC, 0, stream>>>(bnsum + 512, bn_g + 2 * DIMC, bn_b + 2 * DIMC, coef + 512, invN);

    k_segmax_gin_all<<<G, DIMC, 0, stream>>>(h0, h1, h2, coef, start, out);                // groups 0..4
}